// Round 1
// baseline (328.697 us; speedup 1.0000x reference)
//
#include <hip/hip_runtime.h>

// out[s,n, l*4096 + i*64 + j] = norm_l(i,j) * sum_m c_l[s,n,m,i]*c_l[s,n,m,j]
// norm_l = (2l+1)^-1/2 off-diagonal, additionally * 3^-1/2 on diagonal.
// S*N = 24000 pairs, Q=64, output 24000*16384 fp32 = 1.57 GB -> write-BW bound.

#define NTHREADS 256

__global__ __launch_bounds__(NTHREADS) void ps_kernel(
    const float* __restrict__ c0, const float* __restrict__ c1,
    const float* __restrict__ c2, const float* __restrict__ c3,
    float* __restrict__ out, int total)
{
    __shared__ float lds[16 * 64];  // 16 m-rows (l0:0, l1:1..3, l2:4..8, l3:9..15) x 64 q

    const int blk = blockIdx.x;
    if (blk >= total) return;
    const int t = threadIdx.x;

    // ---- stage c into LDS: one float4 per thread (256 float4 = 1024 floats) ----
    {
        const float* src;
        int local;       // float4 index within region
        int ldsbase;     // float index of region start in lds
        if (t < 16)       { src = c0 + (size_t)blk * (1 * 64); local = t;       ldsbase = 0;   }
        else if (t < 64)  { src = c1 + (size_t)blk * (3 * 64); local = t - 16;  ldsbase = 64;  }
        else if (t < 144) { src = c2 + (size_t)blk * (5 * 64); local = t - 64;  ldsbase = 256; }
        else              { src = c3 + (size_t)blk * (7 * 64); local = t - 144; ldsbase = 576; }
        float4 v = reinterpret_cast<const float4*>(src)[local];
        *reinterpret_cast<float4*>(&lds[ldsbase + local * 4]) = v;
    }
    __syncthreads();

    const int jq = t & 15;        // j-quad: columns 4*jq .. 4*jq+3
    const int i0 = t >> 4;        // base row 0..15; rows i0 + 16*r, r=0..3
    const int jbase = jq * 4;

    const float INV_SQRT3 = 0.57735026918962576f;
    // cg = (2l+1)^-1/2, exact fp32 constants
    const float CG[4] = {1.0f, 0.57735026918962576f, 0.44721359549995794f, 0.37796447300922720f};
    const int MOFF[4] = {0, 1, 4, 9};

    float4* outv = reinterpret_cast<float4*>(out);
    const size_t obase4 = (size_t)blk * (16384 / 4);  // float4 index of this pair's output

    #pragma unroll
    for (int l = 0; l < 4; ++l) {
        const int nm = 2 * l + 1;
        const int moff = MOFF[l];
        const float cg = CG[l];

        // per-thread column fragment: cj[m] = c[m][4jq..4jq+3]
        float4 cj[7];
        #pragma unroll
        for (int m = 0; m < nm; ++m)
            cj[m] = *reinterpret_cast<const float4*>(&lds[(moff + m) * 64 + jbase]);

        #pragma unroll
        for (int r = 0; r < 4; ++r) {
            const int i = i0 + r * 16;
            float ax = 0.f, ay = 0.f, az = 0.f, aw = 0.f;
            #pragma unroll
            for (int m = 0; m < nm; ++m) {
                const float ci = lds[(moff + m) * 64 + i];  // broadcast within 16-lane group
                ax += ci * cj[m].x;
                ay += ci * cj[m].y;
                az += ci * cj[m].z;
                aw += ci * cj[m].w;
            }
            // norm: cg everywhere, extra 1/sqrt(3) on the diagonal element (static per component)
            ax *= cg * ((i == jbase + 0) ? INV_SQRT3 : 1.0f);
            ay *= cg * ((i == jbase + 1) ? INV_SQRT3 : 1.0f);
            az *= cg * ((i == jbase + 2) ? INV_SQRT3 : 1.0f);
            aw *= cg * ((i == jbase + 3) ? INV_SQRT3 : 1.0f);

            float4 v; v.x = ax; v.y = ay; v.z = az; v.w = aw;
            outv[obase4 + (size_t)l * 1024 + (size_t)i * 16 + jq] = v;
        }
    }
}

extern "C" void kernel_launch(void* const* d_in, const int* in_sizes, int n_in,
                              void* d_out, int out_size, void* d_ws, size_t ws_size,
                              hipStream_t stream) {
    const float* c0 = (const float*)d_in[0];
    const float* c1 = (const float*)d_in[1];
    const float* c2 = (const float*)d_in[2];
    const float* c3 = (const float*)d_in[3];
    float* out = (float*)d_out;

    const int total = in_sizes[0] / 64;  // S*N pairs (c0 is (S,N,1,64))

    ps_kernel<<<dim3(total), dim3(NTHREADS), 0, stream>>>(c0, c1, c2, c3, out, total);
}